// Round 10
// baseline (325.153 us; speedup 1.0000x reference)
//
#include <hip/hip_runtime.h>

typedef __attribute__((ext_vector_type(8))) short bhalf8_t;   // 8 bf16 bit patterns
typedef __attribute__((ext_vector_type(4))) float f32x4_t;

// Problem constants (B=1, H=W=128, N=4, C=8, OUT=64, M=9, V=81)
// Positions P = B*H*W*N = 65,536.  GEMM: M=P, K=648 pad 672 = 21x32, N=64.
// K permuted: k' = v*8 + c (chunk kc covers views kc*4..kc*4+3, 8 channels each).
#define KCHUNKS 21
#define KSPLIT 3                          // 3 groups x 7 chunks
#define KCPG 7
#define NPOS 65536
#define NBLK 1024                         // NPOS / 64
#define W_BYTES 172032                    // ushort[21][2][4][64][8]
#define VIEW_FLOATS 131072                // 128*128*8
#define CHUNK_BYTES (4 * VIEW_FLOATS * 4) // 2,097,152 B (4 views fp32)

// ---------------------------------------------------------------------------
// Weight prep: WtP[kc][hi|lo][g][o][e] = split-bf16 of conv_w[o][c*81+v],
// v = kc*4+g, c = e (zero-pad v>=81).
// ---------------------------------------------------------------------------
__global__ __launch_bounds__(256) void prep_w_kernel(
    const float* __restrict__ cw, unsigned short* __restrict__ WtP)
{
    const int t = threadIdx.x;
    for (int i = t; i < 672 * 64; i += 256) {
        const int k = i >> 6, o = i & 63;
        const int v = k >> 3, c = k & 7;
        const float val = (v < 81) ? cw[o * 648 + c * 81 + v] : 0.0f;
        const unsigned int u  = __float_as_uint(val);
        const unsigned int hb = u & 0xffff0000u;
        const float r = val - __uint_as_float(hb);
        const unsigned int lb = __float_as_uint(r) & 0xffff0000u;
        const int kc = k >> 5, g = (k >> 3) & 3, e = k & 7;
        const int ix = kc * 4096 + g * 512 + o * 8 + e;
        WtP[ix]        = (unsigned short)(hb >> 16);
        WtP[ix + 2048] = (unsigned short)(lb >> 16);
    }
}

// ---------------------------------------------------------------------------
// Full transpose (single-pass path): img [y][x][c][v] -> T [v][y][x][c] fp32.
// Pow-2 index math only; pitch-85 LDS is conflict-free in both phases.
// ---------------------------------------------------------------------------
__global__ __launch_bounds__(256) void prep_T_all(
    const float* __restrict__ img, float* __restrict__ T)
{
    __shared__ float tile[16 * 8 * 85];   // [x][c][vi]
    const int b = blockIdx.x, t = threadIdx.x;
    const int y = b >> 3, xs = (b & 7) << 4;
    const float* src = img + (size_t)(y * 128 + xs) * 648;
#pragma unroll
    for (int k = 0; k < 64; ++k) {        // 16384 = 16*8*128 slots, vi<81 used
        const int i = t + k * 256;
        const int vi = i & 127;
        const int c = (i >> 7) & 7;
        const int x = i >> 10;
        if (vi < 81)
            tile[(x * 8 + c) * 85 + vi] = src[x * 648 + c * 81 + vi];
    }
    __syncthreads();
#pragma unroll
    for (int k = 0; k < 64; ++k) {
        const int i = t + k * 256;
        const int vi = i >> 7;            // 0..127
        const int x = (i >> 3) & 15;
        const int c = i & 7;
        if (vi < 81)
            T[((size_t)(vi * 128 + y) * 128 + xs + x) * 8 + c] =
                tile[(x * 8 + c) * 85 + vi];
    }
}

// Pre-fill out with bias (K-split groups then pure atomicAdd).
__global__ __launch_bounds__(256) void fill_bias_kernel(
    const float* __restrict__ bias, float* __restrict__ out)
{
    const int t = blockIdx.x * 256 + threadIdx.x;   // 1,048,576 float4s
    const float b = bias[t >> 14];                  // 16384 float4 per o
    ((float4*)out)[t] = make_float4(b, b, b, b);
}

__device__ inline unsigned int pack_pair(float a, float b, unsigned int& lw)
{
    const unsigned int ua = __float_as_uint(a), ub = __float_as_uint(b);
    const unsigned int ha = ua & 0xffff0000u, hb = ub & 0xffff0000u;
    const float ra = a - __uint_as_float(ha);
    const float rb = b - __uint_as_float(hb);
    lw = (__float_as_uint(ra) >> 16) | (__float_as_uint(rb) & 0xffff0000u);
    return (ha >> 16) | hb;
}

// ---------------------------------------------------------------------------
// K-split build: grid (NBLK, KSPLIT). Block = 64 pos x 64 out, 7 K-chunks.
// W fragments read straight from global (L1/L2-resident). atomicAdd epilogue.
// ---------------------------------------------------------------------------
__global__ __launch_bounds__(256) void build_split(
    const float* __restrict__ delt, const float* __restrict__ xg,
    const float* __restrict__ T, const unsigned short* __restrict__ WtP,
    float* __restrict__ out)
{
    __shared__ __align__(16) unsigned short Ahi[4][64][8];   // [g][pos][e]
    __shared__ __align__(16) unsigned short Alo[4][64][8];

    const int t = threadIdx.x;
    const int lane = t & 63;
    const int wv = t >> 6;
    const int kc0 = blockIdx.y * KCPG;
    const int pos_g = blockIdx.x * 64 + lane;        // < 65536
    const int h = pos_g >> 9;
    const int w = (pos_g >> 2) & 127;

    const float dlt = delt[pos_g];
    // ix = ((gx+1)*128-1)/2 with gx = bx + 2(4-uu)/128*dlt  ==>
    // ix = ix0 + (4-uu)*dlt,  ix0 = 128*w/127 - 0.5
    const float ix0 = fmaf((float)w, 128.0f / 127.0f, -0.5f);
    const float iy0 = fmaf((float)h, 128.0f / 127.0f, -0.5f);
    const int xgbase = (h * 128 + w) * 81;

    f32x4_t acc[2][2];
#pragma unroll
    for (int i = 0; i < 2; ++i)
#pragma unroll
        for (int j = 0; j < 2; ++j) acc[i][j] = (f32x4_t)0.0f;

    const int mrow = (wv & 1) * 32;
    const int ncol = (wv >> 1) * 32;
    const int frow = lane & 15;
    const int fg = lane >> 4;

    // incremental view index state (v += 4 per chunk; uu=v%9, vv=v/9)
    int v = kc0 * 4 + wv;
    int uu = v % 9;                       // compile-time divisor -> magic mul
    float fu = (float)(4 - uu);
    float fv = (float)(4 - (v / 9));

    for (int ci = 0; ci < KCPG; ++ci) {
        const int kc = kc0 + ci;
        float sc0=0.f,sc1=0.f,sc2=0.f,sc3=0.f,sc4=0.f,sc5=0.f,sc6=0.f,sc7=0.f;
        float gate = 0.0f;
        if (v < 81) {
            gate = xg[xgbase + v];
            const float ix = fmaf(fu, dlt, ix0);
            const float iy = fmaf(fv, dlt, iy0);
            const float x0f = floorf(ix), y0f = floorf(iy);
            const float wx1 = ix - x0f, wy1 = iy - y0f;
            const float wx0 = 1.0f - wx1, wy0 = 1.0f - wy1;
            const int x0 = (int)x0f, y0 = (int)y0f;
            const int x1 = x0 + 1, y1 = y0 + 1;
            const float ex0 = (x0 >= 0 && x0 < 128) ? wx0 : 0.0f;
            const float ex1 = (x1 >= 0 && x1 < 128) ? wx1 : 0.0f;
            const float ey0 = (y0 >= 0 && y0 < 128) ? wy0 : 0.0f;
            const float ey1 = (y1 >= 0 && y1 < 128) ? wy1 : 0.0f;
            const int xc0 = min(max(x0, 0), 127), xc1 = min(max(x1, 0), 127);
            const int yc0 = min(max(y0, 0), 127), yc1 = min(max(y1, 0), 127);
            const float* bv = T + (size_t)v * VIEW_FLOATS;
            const float4* p00 = (const float4*)(bv + (yc0 * 128 + xc0) * 8);
            const float4* p01 = (const float4*)(bv + (yc0 * 128 + xc1) * 8);
            const float4* p10 = (const float4*)(bv + (yc1 * 128 + xc0) * 8);
            const float4* p11 = (const float4*)(bv + (yc1 * 128 + xc1) * 8);
            const float w00 = ex0 * ey0, w01 = ex1 * ey0;
            const float w10 = ex0 * ey1, w11 = ex1 * ey1;
            const float4 a00 = p00[0], b00 = p00[1];
            const float4 a01 = p01[0], b01 = p01[1];
            const float4 a10 = p10[0], b10 = p10[1];
            const float4 a11 = p11[0], b11 = p11[1];
            sc0 = fmaf(w11, a11.x, fmaf(w10, a10.x, fmaf(w01, a01.x, w00 * a00.x)));
            sc1 = fmaf(w11, a11.y, fmaf(w10, a10.y, fmaf(w01, a01.y, w00 * a00.y)));
            sc2 = fmaf(w11, a11.z, fmaf(w10, a10.z, fmaf(w01, a01.z, w00 * a00.z)));
            sc3 = fmaf(w11, a11.w, fmaf(w10, a10.w, fmaf(w01, a01.w, w00 * a00.w)));
            sc4 = fmaf(w11, b11.x, fmaf(w10, b10.x, fmaf(w01, b01.x, w00 * b00.x)));
            sc5 = fmaf(w11, b11.y, fmaf(w10, b10.y, fmaf(w01, b01.y, w00 * b00.y)));
            sc6 = fmaf(w11, b11.z, fmaf(w10, b10.z, fmaf(w01, b01.z, w00 * b00.z)));
            sc7 = fmaf(w11, b11.w, fmaf(w10, b10.w, fmaf(w01, b01.w, w00 * b00.w)));
        }
        const float g0 = sc0 * gate, g1 = sc1 * gate, g2 = sc2 * gate, g3 = sc3 * gate;
        const float g4 = sc4 * gate, g5 = sc5 * gate, g6 = sc6 * gate, g7 = sc7 * gate;
        unsigned int lw0, lw1, lw2, lw3;
        const unsigned int hw0 = pack_pair(g0, g1, lw0);
        const unsigned int hw1 = pack_pair(g2, g3, lw1);
        const unsigned int hw2 = pack_pair(g4, g5, lw2);
        const unsigned int hw3 = pack_pair(g6, g7, lw3);
        *(uint4*)(&Ahi[wv][lane][0]) = make_uint4(hw0, hw1, hw2, hw3);
        *(uint4*)(&Alo[wv][lane][0]) = make_uint4(lw0, lw1, lw2, lw3);

        __syncthreads();

        bhalf8_t fa_hi[2], fa_lo[2], fw_hi[2], fw_lo[2];
#pragma unroll
        for (int i = 0; i < 2; ++i) {
            const int r = mrow + i * 16 + frow;
            fa_hi[i] = *(const bhalf8_t*)(&Ahi[fg][r][0]);
            fa_lo[i] = *(const bhalf8_t*)(&Alo[fg][r][0]);
        }
        const unsigned short* wbase = WtP + kc * 4096 + fg * 512;
#pragma unroll
        for (int j = 0; j < 2; ++j) {
            const int o = ncol + j * 16 + frow;
            fw_hi[j] = *(const bhalf8_t*)(wbase + o * 8);
            fw_lo[j] = *(const bhalf8_t*)(wbase + 2048 + o * 8);
        }
#pragma unroll
        for (int i = 0; i < 2; ++i)
#pragma unroll
            for (int j = 0; j < 2; ++j) {
                acc[i][j] = __builtin_amdgcn_mfma_f32_16x16x32_bf16(fa_hi[i], fw_hi[j], acc[i][j], 0, 0, 0);
                acc[i][j] = __builtin_amdgcn_mfma_f32_16x16x32_bf16(fa_lo[i], fw_hi[j], acc[i][j], 0, 0, 0);
                acc[i][j] = __builtin_amdgcn_mfma_f32_16x16x32_bf16(fa_hi[i], fw_lo[j], acc[i][j], 0, 0, 0);
            }
        __syncthreads();

        // advance v by 4: uu wraps mod 9, vv bumps on wrap
        v += 4;
        const bool wrap = (uu + 4) >= 9;
        uu = uu + 4 - (wrap ? 9 : 0);
        fu += wrap ? 5.0f : -4.0f;
        fv -= wrap ? 1.0f : 0.0f;
    }

    // D layout: col(=o)=lane&15, row(=pos)=(lane>>4)*4+reg ; atomic accumulate.
#pragma unroll
    for (int j = 0; j < 2; ++j) {
        const int o = ncol + j * 16 + frow;
#pragma unroll
        for (int i = 0; i < 2; ++i) {
            const int posb = blockIdx.x * 64 + mrow + i * 16 + (lane >> 4) * 4;
            float* dst = out + (size_t)o * NPOS + posb;
#pragma unroll
            for (int r = 0; r < 4; ++r)
                atomicAdd(dst + r, acc[i][j][r]);
        }
    }
}

// ---------------------------------------------------------------------------
// Multi-pass fallback (small ws): original transpose + non-atomic build.
// ---------------------------------------------------------------------------
__global__ __launch_bounds__(256) void prep_T_pass(
    const float* __restrict__ img, float* __restrict__ T, int v0, int nv)
{
    __shared__ float tile[16 * 8 * 85];
    const int b = blockIdx.x, t = threadIdx.x;
    const int y = b >> 3, xs = (b & 7) << 4;
    const int total = 16 * 8 * nv;
    const float* src = img + (size_t)(y * 128 + xs) * 648;
    for (int i = t; i < total; i += 256) {
        const int x = i / (8 * nv);
        const int rem = i - x * (8 * nv);
        const int c = rem / nv;
        const int vi = rem - c * nv;
        tile[(x * 8 + c) * 85 + vi] = src[x * 648 + c * 81 + v0 + vi];
    }
    __syncthreads();
    for (int i = t; i < total; i += 256) {
        const int vi = i >> 7;
        const int x = (i >> 3) & 15;
        const int c = i & 7;
        T[((size_t)(vi * 128 + y) * 128 + xs + x) * 8 + c] = tile[(x * 8 + c) * 85 + vi];
    }
}

__global__ __launch_bounds__(256) void build_pass(
    const float* __restrict__ delt, const float* __restrict__ xg,
    const float* __restrict__ T, const unsigned short* __restrict__ WtP,
    const float* __restrict__ bias, float* __restrict__ out,
    int kc0, int nkc, int first)
{
    __shared__ __align__(16) unsigned short Ahi[4][64][8];
    __shared__ __align__(16) unsigned short Alo[4][64][8];

    const int t = threadIdx.x;
    const int lane = t & 63;
    const int wv = t >> 6;
    const int pos_g = blockIdx.x * 64 + lane;
    const int h = pos_g >> 9;
    const int w = (pos_g >> 2) & 127;

    const float dlt = delt[pos_g];
    const float ix0 = fmaf((float)w, 128.0f / 127.0f, -0.5f);
    const float iy0 = fmaf((float)h, 128.0f / 127.0f, -0.5f);
    const int xgbase = (h * 128 + w) * 81;

    f32x4_t acc[2][2];
#pragma unroll
    for (int i = 0; i < 2; ++i)
#pragma unroll
        for (int j = 0; j < 2; ++j) acc[i][j] = (f32x4_t)0.0f;

    const int mrow = (wv & 1) * 32;
    const int ncol = (wv >> 1) * 32;
    const int frow = lane & 15;
    const int fg = lane >> 4;

    for (int ci = 0; ci < nkc; ++ci) {
        const int kc = kc0 + ci;
        const int v = kc * 4 + wv;
        float sc0=0.f,sc1=0.f,sc2=0.f,sc3=0.f,sc4=0.f,sc5=0.f,sc6=0.f,sc7=0.f;
        float gate = 0.0f;
        if (v < 81) {
            gate = xg[xgbase + v];
            const int uu = v % 9, vv = v / 9;
            const float ix = fmaf((float)(4 - uu), dlt, ix0);
            const float iy = fmaf((float)(4 - vv), dlt, iy0);
            const float x0f = floorf(ix), y0f = floorf(iy);
            const float wx1 = ix - x0f, wy1 = iy - y0f;
            const float wx0 = 1.0f - wx1, wy0 = 1.0f - wy1;
            const int x0 = (int)x0f, y0 = (int)y0f;
            const int x1 = x0 + 1, y1 = y0 + 1;
            const float ex0 = (x0 >= 0 && x0 < 128) ? wx0 : 0.0f;
            const float ex1 = (x1 >= 0 && x1 < 128) ? wx1 : 0.0f;
            const float ey0 = (y0 >= 0 && y0 < 128) ? wy0 : 0.0f;
            const float ey1 = (y1 >= 0 && y1 < 128) ? wy1 : 0.0f;
            const int xc0 = min(max(x0, 0), 127), xc1 = min(max(x1, 0), 127);
            const int yc0 = min(max(y0, 0), 127), yc1 = min(max(y1, 0), 127);
            const float* bv = T + (size_t)(ci * 4 + wv) * VIEW_FLOATS;
            const float4* p00 = (const float4*)(bv + (yc0 * 128 + xc0) * 8);
            const float4* p01 = (const float4*)(bv + (yc0 * 128 + xc1) * 8);
            const float4* p10 = (const float4*)(bv + (yc1 * 128 + xc0) * 8);
            const float4* p11 = (const float4*)(bv + (yc1 * 128 + xc1) * 8);
            const float w00 = ex0 * ey0, w01 = ex1 * ey0;
            const float w10 = ex0 * ey1, w11 = ex1 * ey1;
            const float4 a00 = p00[0], b00 = p00[1];
            const float4 a01 = p01[0], b01 = p01[1];
            const float4 a10 = p10[0], b10 = p10[1];
            const float4 a11 = p11[0], b11 = p11[1];
            sc0 = fmaf(w11, a11.x, fmaf(w10, a10.x, fmaf(w01, a01.x, w00 * a00.x)));
            sc1 = fmaf(w11, a11.y, fmaf(w10, a10.y, fmaf(w01, a01.y, w00 * a00.y)));
            sc2 = fmaf(w11, a11.z, fmaf(w10, a10.z, fmaf(w01, a01.z, w00 * a00.z)));
            sc3 = fmaf(w11, a11.w, fmaf(w10, a10.w, fmaf(w01, a01.w, w00 * a00.w)));
            sc4 = fmaf(w11, b11.x, fmaf(w10, b10.x, fmaf(w01, b01.x, w00 * b00.x)));
            sc5 = fmaf(w11, b11.y, fmaf(w10, b10.y, fmaf(w01, b01.y, w00 * b00.y)));
            sc6 = fmaf(w11, b11.z, fmaf(w10, b10.z, fmaf(w01, b01.z, w00 * b00.z)));
            sc7 = fmaf(w11, b11.w, fmaf(w10, b10.w, fmaf(w01, b01.w, w00 * b00.w)));
        }
        const float g0 = sc0 * gate, g1 = sc1 * gate, g2 = sc2 * gate, g3 = sc3 * gate;
        const float g4 = sc4 * gate, g5 = sc5 * gate, g6 = sc6 * gate, g7 = sc7 * gate;
        unsigned int lw0, lw1, lw2, lw3;
        const unsigned int hw0 = pack_pair(g0, g1, lw0);
        const unsigned int hw1 = pack_pair(g2, g3, lw1);
        const unsigned int hw2 = pack_pair(g4, g5, lw2);
        const unsigned int hw3 = pack_pair(g6, g7, lw3);
        *(uint4*)(&Ahi[wv][lane][0]) = make_uint4(hw0, hw1, hw2, hw3);
        *(uint4*)(&Alo[wv][lane][0]) = make_uint4(lw0, lw1, lw2, lw3);

        __syncthreads();

        bhalf8_t fa_hi[2], fa_lo[2], fw_hi[2], fw_lo[2];
#pragma unroll
        for (int i = 0; i < 2; ++i) {
            const int r = mrow + i * 16 + frow;
            fa_hi[i] = *(const bhalf8_t*)(&Ahi[fg][r][0]);
            fa_lo[i] = *(const bhalf8_t*)(&Alo[fg][r][0]);
        }
        const unsigned short* wbase = WtP + kc * 4096 + fg * 512;
#pragma unroll
        for (int j = 0; j < 2; ++j) {
            const int o = ncol + j * 16 + frow;
            fw_hi[j] = *(const bhalf8_t*)(wbase + o * 8);
            fw_lo[j] = *(const bhalf8_t*)(wbase + 2048 + o * 8);
        }
#pragma unroll
        for (int i = 0; i < 2; ++i)
#pragma unroll
            for (int j = 0; j < 2; ++j) {
                acc[i][j] = __builtin_amdgcn_mfma_f32_16x16x32_bf16(fa_hi[i], fw_hi[j], acc[i][j], 0, 0, 0);
                acc[i][j] = __builtin_amdgcn_mfma_f32_16x16x32_bf16(fa_lo[i], fw_hi[j], acc[i][j], 0, 0, 0);
                acc[i][j] = __builtin_amdgcn_mfma_f32_16x16x32_bf16(fa_hi[i], fw_lo[j], acc[i][j], 0, 0, 0);
            }
        __syncthreads();
    }

#pragma unroll
    for (int j = 0; j < 2; ++j) {
        const int o = ncol + j * 16 + frow;
        const float bb = bias[o];
#pragma unroll
        for (int i = 0; i < 2; ++i) {
            const int posb = blockIdx.x * 64 + mrow + i * 16 + (lane >> 4) * 4;
            float* dst = out + (size_t)o * NPOS + posb;
            if (first) {
                *(float4*)dst = make_float4(acc[i][j][0] + bb, acc[i][j][1] + bb,
                                            acc[i][j][2] + bb, acc[i][j][3] + bb);
            } else {
                float4 cur = *(const float4*)dst;
                *(float4*)dst = make_float4(cur.x + acc[i][j][0], cur.y + acc[i][j][1],
                                            cur.z + acc[i][j][2], cur.w + acc[i][j][3]);
            }
        }
    }
}

// ---------------------------------------------------------------------------
// Ultra-fallback (no workspace): gather from native [y][x][c][v] layout.
// ---------------------------------------------------------------------------
__global__ __launch_bounds__(256) void build_direct(
    const float* __restrict__ delt, const float* __restrict__ xg,
    const float* __restrict__ img, const float* __restrict__ cw,
    const float* __restrict__ bias, float* __restrict__ out)
{
    __shared__ __align__(16) unsigned short Ahi[4][64][8];
    __shared__ __align__(16) unsigned short Alo[4][64][8];

    const int t = threadIdx.x;
    const int lane = t & 63;
    const int wv = t >> 6;
    const int pos_g = blockIdx.x * 64 + lane;
    const int h = pos_g >> 9;
    const int w = (pos_g >> 2) & 127;

    const float dlt = delt[pos_g];
    const float ix0 = fmaf((float)w, 128.0f / 127.0f, -0.5f);
    const float iy0 = fmaf((float)h, 128.0f / 127.0f, -0.5f);
    const int xgbase = (h * 128 + w) * 81;

    f32x4_t acc[2][2];
#pragma unroll
    for (int i = 0; i < 2; ++i)
#pragma unroll
        for (int j = 0; j < 2; ++j) acc[i][j] = (f32x4_t)0.0f;

    const int mrow = (wv & 1) * 32;
    const int ncol = (wv >> 1) * 32;
    const int frow = lane & 15;
    const int fg = lane >> 4;

    for (int kc = 0; kc < KCHUNKS; ++kc) {
        const int v = kc * 4 + wv;
        float sc[8];
#pragma unroll
        for (int c = 0; c < 8; ++c) sc[c] = 0.0f;
        float gate = 0.0f;
        if (v < 81) {
            gate = xg[xgbase + v];
            const int uu = v % 9, vv = v / 9;
            const float ix = fmaf((float)(4 - uu), dlt, ix0);
            const float iy = fmaf((float)(4 - vv), dlt, iy0);
            const float x0f = floorf(ix), y0f = floorf(iy);
            const float wx1 = ix - x0f, wy1 = iy - y0f;
            const float wx0 = 1.0f - wx1, wy0 = 1.0f - wy1;
            const int x0 = (int)x0f, y0 = (int)y0f;
            const int x1 = x0 + 1, y1 = y0 + 1;
            const float ex0 = (x0 >= 0 && x0 < 128) ? wx0 : 0.0f;
            const float ex1 = (x1 >= 0 && x1 < 128) ? wx1 : 0.0f;
            const float ey0 = (y0 >= 0 && y0 < 128) ? wy0 : 0.0f;
            const float ey1 = (y1 >= 0 && y1 < 128) ? wy1 : 0.0f;
            const int xc0 = min(max(x0, 0), 127), xc1 = min(max(x1, 0), 127);
            const int yc0 = min(max(y0, 0), 127), yc1 = min(max(y1, 0), 127);
            const float cwt[4] = {ex0 * ey0, ex1 * ey0, ex0 * ey1, ex1 * ey1};
            const int cyx[4] = {yc0 * 128 + xc0, yc0 * 128 + xc1,
                                yc1 * 128 + xc0, yc1 * 128 + xc1};
#pragma unroll
            for (int k = 0; k < 4; ++k) {
                const float* p = img + (size_t)cyx[k] * 648 + v;
#pragma unroll
                for (int c = 0; c < 8; ++c)
                    sc[c] = fmaf(cwt[k], p[c * 81], sc[c]);
            }
        }
        unsigned int hw[4], lw[4];
#pragma unroll
        for (int q = 0; q < 4; ++q)
            hw[q] = pack_pair(sc[2 * q] * gate, sc[2 * q + 1] * gate, lw[q]);
        *(uint4*)(&Ahi[wv][lane][0]) = make_uint4(hw[0], hw[1], hw[2], hw[3]);
        *(uint4*)(&Alo[wv][lane][0]) = make_uint4(lw[0], lw[1], lw[2], lw[3]);

        __syncthreads();

        const int vW = kc * 4 + fg;
        bhalf8_t fw_hi[2], fw_lo[2];
#pragma unroll
        for (int j = 0; j < 2; ++j) {
            const int o = ncol + j * 16 + frow;
#pragma unroll
            for (int e = 0; e < 8; ++e) {
                const float val = (vW < 81) ? cw[o * 648 + e * 81 + vW] : 0.0f;
                const unsigned int hb = __float_as_uint(val) & 0xffff0000u;
                const float r = val - __uint_as_float(hb);
                fw_hi[j][e] = (short)(hb >> 16);
                fw_lo[j][e] = (short)(__float_as_uint(r) >> 16);
            }
        }
        bhalf8_t fa_hi[2], fa_lo[2];
#pragma unroll
        for (int i = 0; i < 2; ++i) {
            const int r = mrow + i * 16 + frow;
            fa_hi[i] = *(const bhalf8_t*)(&Ahi[fg][r][0]);
            fa_lo[i] = *(const bhalf8_t*)(&Alo[fg][r][0]);
        }
#pragma unroll
        for (int i = 0; i < 2; ++i)
#pragma unroll
            for (int j = 0; j < 2; ++j) {
                acc[i][j] = __builtin_amdgcn_mfma_f32_16x16x32_bf16(fa_hi[i], fw_hi[j], acc[i][j], 0, 0, 0);
                acc[i][j] = __builtin_amdgcn_mfma_f32_16x16x32_bf16(fa_lo[i], fw_hi[j], acc[i][j], 0, 0, 0);
                acc[i][j] = __builtin_amdgcn_mfma_f32_16x16x32_bf16(fa_hi[i], fw_lo[j], acc[i][j], 0, 0, 0);
            }
        __syncthreads();
    }

#pragma unroll
    for (int j = 0; j < 2; ++j) {
        const int o = ncol + j * 16 + frow;
        const float bb = bias[o];
#pragma unroll
        for (int i = 0; i < 2; ++i) {
            const int posb = blockIdx.x * 64 + mrow + i * 16 + (lane >> 4) * 4;
            float* dst = out + (size_t)o * NPOS + posb;
            *(float4*)dst = make_float4(acc[i][j][0] + bb, acc[i][j][1] + bb,
                                        acc[i][j][2] + bb, acc[i][j][3] + bb);
        }
    }
}

extern "C" void kernel_launch(void* const* d_in, const int* in_sizes, int n_in,
                              void* d_out, int out_size, void* d_ws, size_t ws_size,
                              hipStream_t stream)
{
    const float* deltmap = (const float*)d_in[0];
    const float* image   = (const float*)d_in[1];
    const float* xgp     = (const float*)d_in[2];
    const float* cw      = (const float*)d_in[3];
    const float* cb      = (const float*)d_in[4];
    float* outp = (float*)d_out;

    long long availT = (long long)ws_size - (long long)W_BYTES;
    int G = 0;
    if (availT > 0) {
        long long g = availT / CHUNK_BYTES;
        G = (g > 21) ? 21 : (int)g;
    }

    unsigned short* WtP = (unsigned short*)d_ws;
    float* T = (float*)((char*)d_ws + W_BYTES);

    if (G >= 21) {
        // single-pass fast path: full transpose + K-split atomic build
        prep_w_kernel<<<1, 256, 0, stream>>>(cw, WtP);
        prep_T_all<<<1024, 256, 0, stream>>>(image, T);
        fill_bias_kernel<<<4096, 256, 0, stream>>>(cb, outp);
        build_split<<<dim3(NBLK, KSPLIT), 256, 0, stream>>>(deltmap, xgp, T, WtP, outp);
    } else if (G >= 1) {
        prep_w_kernel<<<1, 256, 0, stream>>>(cw, WtP);
        int first = 1;
        for (int kc0 = 0; kc0 < KCHUNKS; kc0 += G) {
            const int nkc = (KCHUNKS - kc0 < G) ? (KCHUNKS - kc0) : G;
            const int v0 = kc0 * 4;
            int nv = 81 - v0;
            if (nv > nkc * 4) nv = nkc * 4;
            prep_T_pass<<<1024, 256, 0, stream>>>(image, T, v0, nv);
            build_pass<<<NBLK, 256, 0, stream>>>(deltmap, xgp, T, WtP, cb, outp,
                                                 kc0, nkc, first);
            first = 0;
        }
    } else {
        build_direct<<<NBLK, 256, 0, stream>>>(deltmap, xgp, image, cw, cb, outp);
    }
}

// Round 11
// 176.060 us; speedup vs baseline: 1.8468x; 1.8468x over previous
//
#include <hip/hip_runtime.h>

typedef __attribute__((ext_vector_type(8))) short bhalf8_t;   // 8 bf16 bit patterns
typedef __attribute__((ext_vector_type(4))) float f32x4_t;

// Problem constants (B=1, H=W=128, N=4, C=8, OUT=64, M=9, V=81)
// Positions P = 65,536. GEMM: M=P, K=648 pad 672 = 21x32, N=64. k' = v*8+c.
#define KCHUNKS 21
#define NPOS 65536
#define NBLK 1024                         // NPOS / 64
#define W_BYTES 172032                    // ushort[21][2][4][64][8]
#define T_BYTES 42467328                  // 81*128*128*8*4
#define PART_BYTES 16777216               // 64*65536*4
#define VIEW_FLOATS 131072                // 128*128*8
#define CHUNK_BYTES (4 * VIEW_FLOATS * 4)

// ---------------------------------------------------------------------------
// Weight prep: 64 blocks (one per o). Row staged coalesced in LDS, then
// WtP[kc][hi|lo][g][o][e] = split-bf16 of conv_w[o][c*81+v], v=kc*4+g, c=e.
// ---------------------------------------------------------------------------
__global__ __launch_bounds__(256) void prep_w_kernel(
    const float* __restrict__ cw, unsigned short* __restrict__ WtP)
{
    __shared__ float row[648];
    const int o = blockIdx.x, t = threadIdx.x;
    for (int i = t; i < 648; i += 256) row[i] = cw[o * 648 + i];
    __syncthreads();
    for (int k = t; k < 672; k += 256) {
        const int v = k >> 3, c = k & 7;
        const float val = (v < 81) ? row[c * 81 + v] : 0.0f;
        const unsigned int hb = __float_as_uint(val) & 0xffff0000u;
        const float r = val - __uint_as_float(hb);
        const unsigned int lb = __float_as_uint(r) & 0xffff0000u;
        const int kc = k >> 5, g = (k >> 3) & 3, e = k & 7;
        const int ix = kc * 4096 + g * 512 + o * 8 + e;
        WtP[ix]        = (unsigned short)(hb >> 16);
        WtP[ix + 2048] = (unsigned short)(lb >> 16);
    }
}

// ---------------------------------------------------------------------------
// Full transpose: img [y][x][c][v] -> T [v][y][x][c] fp32 (pow-2 math only).
// ---------------------------------------------------------------------------
__global__ __launch_bounds__(256) void prep_T_all(
    const float* __restrict__ img, float* __restrict__ T)
{
    __shared__ float tile[16 * 8 * 85];   // [x][c][vi], odd pitch
    const int b = blockIdx.x, t = threadIdx.x;
    const int y = b >> 3, xs = (b & 7) << 4;
    const float* src = img + (size_t)(y * 128 + xs) * 648;
#pragma unroll
    for (int k = 0; k < 64; ++k) {
        const int i = t + k * 256;
        const int vi = i & 127;
        const int c = (i >> 7) & 7;
        const int x = i >> 10;
        if (vi < 81)
            tile[(x * 8 + c) * 85 + vi] = src[x * 648 + c * 81 + vi];
    }
    __syncthreads();
#pragma unroll
    for (int k = 0; k < 64; ++k) {
        const int i = t + k * 256;
        const int vi = i >> 7;
        const int x = (i >> 3) & 15;
        const int c = i & 7;
        if (vi < 81)
            T[((size_t)(vi * 128 + y) * 128 + xs + x) * 8 + c] =
                tile[(x * 8 + c) * 85 + vi];
    }
}

__device__ inline unsigned int pack_pair(float a, float b, unsigned int& lw)
{
    const unsigned int ha = __float_as_uint(a) & 0xffff0000u;
    const unsigned int hb = __float_as_uint(b) & 0xffff0000u;
    const float ra = a - __uint_as_float(ha);
    const float rb = b - __uint_as_float(hb);
    lw = (__float_as_uint(ra) >> 16) | (__float_as_uint(rb) & 0xffff0000u);
    return (ha >> 16) | hb;
}

// ---------------------------------------------------------------------------
// K-split build, NO atomics: grid (NBLK, split). Group 0 -> out (+bias),
// group 1 -> part (raw). split==1 covers all 21 chunks -> out (+bias).
// ---------------------------------------------------------------------------
__global__ __launch_bounds__(256) void build_ksplit(
    const float* __restrict__ delt, const float* __restrict__ xg,
    const float* __restrict__ T, const unsigned short* __restrict__ WtP,
    const float* __restrict__ bias, float* __restrict__ out,
    float* __restrict__ part, int split)
{
    __shared__ __align__(16) unsigned short Ahi[4][64][8];   // [g][pos][e]
    __shared__ __align__(16) unsigned short Alo[4][64][8];

    const int t = threadIdx.x;
    const int lane = t & 63;
    const int wv = t >> 6;
    const int grp = blockIdx.y;
    const int kc0 = (split == 2) ? grp * 11 : 0;
    const int nkc = (split == 2) ? (grp == 0 ? 11 : 10) : KCHUNKS;
    float* dst_base = (grp == 0) ? out : part;
    const int addbias = (grp == 0);

    const int pos_g = blockIdx.x * 64 + lane;        // < 65536
    const int h = pos_g >> 9;
    const int w = (pos_g >> 2) & 127;

    const float dlt = delt[pos_g];
    const float ix0 = fmaf((float)w, 128.0f / 127.0f, -0.5f);
    const float iy0 = fmaf((float)h, 128.0f / 127.0f, -0.5f);
    const int xgbase = (h * 128 + w) * 81;

    f32x4_t acc[2][2];
#pragma unroll
    for (int i = 0; i < 2; ++i)
#pragma unroll
        for (int j = 0; j < 2; ++j) acc[i][j] = (f32x4_t)0.0f;

    const int mrow = (wv & 1) * 32;
    const int ncol = (wv >> 1) * 32;
    const int frow = lane & 15;
    const int fg = lane >> 4;

    for (int ci = 0; ci < nkc; ++ci) {
        const int kc = kc0 + ci;
        const int v = kc * 4 + wv;
        float sc0=0.f,sc1=0.f,sc2=0.f,sc3=0.f,sc4=0.f,sc5=0.f,sc6=0.f,sc7=0.f;
        float gate = 0.0f;
        if (v < 81) {
            gate = xg[xgbase + v];
            const int uu = v % 9, vv = v / 9;
            const float ix = fmaf((float)(4 - uu), dlt, ix0);
            const float iy = fmaf((float)(4 - vv), dlt, iy0);
            const float x0f = floorf(ix), y0f = floorf(iy);
            const float wx1 = ix - x0f, wy1 = iy - y0f;
            const float wx0 = 1.0f - wx1, wy0 = 1.0f - wy1;
            const int x0 = (int)x0f, y0 = (int)y0f;
            const int x1 = x0 + 1, y1 = y0 + 1;
            const float ex0 = (x0 >= 0 && x0 < 128) ? wx0 : 0.0f;
            const float ex1 = (x1 >= 0 && x1 < 128) ? wx1 : 0.0f;
            const float ey0 = (y0 >= 0 && y0 < 128) ? wy0 : 0.0f;
            const float ey1 = (y1 >= 0 && y1 < 128) ? wy1 : 0.0f;
            const int xc0 = min(max(x0, 0), 127), xc1 = min(max(x1, 0), 127);
            const int yc0 = min(max(y0, 0), 127), yc1 = min(max(y1, 0), 127);
            const float* bv = T + (size_t)v * VIEW_FLOATS;
            const float4* p00 = (const float4*)(bv + (yc0 * 128 + xc0) * 8);
            const float4* p01 = (const float4*)(bv + (yc0 * 128 + xc1) * 8);
            const float4* p10 = (const float4*)(bv + (yc1 * 128 + xc0) * 8);
            const float4* p11 = (const float4*)(bv + (yc1 * 128 + xc1) * 8);
            const float w00 = ex0 * ey0, w01 = ex1 * ey0;
            const float w10 = ex0 * ey1, w11 = ex1 * ey1;
            const float4 a00 = p00[0], b00 = p00[1];
            const float4 a01 = p01[0], b01 = p01[1];
            const float4 a10 = p10[0], b10 = p10[1];
            const float4 a11 = p11[0], b11 = p11[1];
            sc0 = fmaf(w11, a11.x, fmaf(w10, a10.x, fmaf(w01, a01.x, w00 * a00.x)));
            sc1 = fmaf(w11, a11.y, fmaf(w10, a10.y, fmaf(w01, a01.y, w00 * a00.y)));
            sc2 = fmaf(w11, a11.z, fmaf(w10, a10.z, fmaf(w01, a01.z, w00 * a00.z)));
            sc3 = fmaf(w11, a11.w, fmaf(w10, a10.w, fmaf(w01, a01.w, w00 * a00.w)));
            sc4 = fmaf(w11, b11.x, fmaf(w10, b10.x, fmaf(w01, b01.x, w00 * b00.x)));
            sc5 = fmaf(w11, b11.y, fmaf(w10, b10.y, fmaf(w01, b01.y, w00 * b00.y)));
            sc6 = fmaf(w11, b11.z, fmaf(w10, b10.z, fmaf(w01, b01.z, w00 * b00.z)));
            sc7 = fmaf(w11, b11.w, fmaf(w10, b10.w, fmaf(w01, b01.w, w00 * b00.w)));
        }
        const float g0 = sc0 * gate, g1 = sc1 * gate, g2 = sc2 * gate, g3 = sc3 * gate;
        const float g4 = sc4 * gate, g5 = sc5 * gate, g6 = sc6 * gate, g7 = sc7 * gate;
        unsigned int lw0, lw1, lw2, lw3;
        const unsigned int hw0 = pack_pair(g0, g1, lw0);
        const unsigned int hw1 = pack_pair(g2, g3, lw1);
        const unsigned int hw2 = pack_pair(g4, g5, lw2);
        const unsigned int hw3 = pack_pair(g6, g7, lw3);
        *(uint4*)(&Ahi[wv][lane][0]) = make_uint4(hw0, hw1, hw2, hw3);
        *(uint4*)(&Alo[wv][lane][0]) = make_uint4(lw0, lw1, lw2, lw3);

        __syncthreads();

        bhalf8_t fa_hi[2], fa_lo[2], fw_hi[2], fw_lo[2];
#pragma unroll
        for (int i = 0; i < 2; ++i) {
            const int r = mrow + i * 16 + frow;
            fa_hi[i] = *(const bhalf8_t*)(&Ahi[fg][r][0]);
            fa_lo[i] = *(const bhalf8_t*)(&Alo[fg][r][0]);
        }
        const unsigned short* wbase = WtP + kc * 4096 + fg * 512;
#pragma unroll
        for (int j = 0; j < 2; ++j) {
            const int o = ncol + j * 16 + frow;
            fw_hi[j] = *(const bhalf8_t*)(wbase + o * 8);
            fw_lo[j] = *(const bhalf8_t*)(wbase + 2048 + o * 8);
        }
#pragma unroll
        for (int i = 0; i < 2; ++i)
#pragma unroll
            for (int j = 0; j < 2; ++j) {
                acc[i][j] = __builtin_amdgcn_mfma_f32_16x16x32_bf16(fa_hi[i], fw_hi[j], acc[i][j], 0, 0, 0);
                acc[i][j] = __builtin_amdgcn_mfma_f32_16x16x32_bf16(fa_lo[i], fw_hi[j], acc[i][j], 0, 0, 0);
                acc[i][j] = __builtin_amdgcn_mfma_f32_16x16x32_bf16(fa_hi[i], fw_lo[j], acc[i][j], 0, 0, 0);
            }
        __syncthreads();
    }

    // D layout: col(=o)=lane&15, row(=pos)=(lane>>4)*4+reg ; plain float4 store.
#pragma unroll
    for (int j = 0; j < 2; ++j) {
        const int o = ncol + j * 16 + frow;
        const float bb = addbias ? bias[o] : 0.0f;
#pragma unroll
        for (int i = 0; i < 2; ++i) {
            const int posb = blockIdx.x * 64 + mrow + i * 16 + (lane >> 4) * 4;
            float* dst = dst_base + (size_t)o * NPOS + posb;
            *(float4*)dst = make_float4(acc[i][j][0] + bb, acc[i][j][1] + bb,
                                        acc[i][j][2] + bb, acc[i][j][3] + bb);
        }
    }
}

// out += part (50 MB streaming)
__global__ __launch_bounds__(256) void reduce_kernel(
    const float* __restrict__ part, float* __restrict__ out)
{
    const int i = blockIdx.x * 256 + threadIdx.x;   // 1,048,576 float4
    const float4 a = ((const float4*)out)[i];
    const float4 b = ((const float4*)part)[i];
    ((float4*)out)[i] = make_float4(a.x + b.x, a.y + b.y, a.z + b.z, a.w + b.w);
}

// ---------------------------------------------------------------------------
// Multi-pass fallback (small ws) and no-ws fallback — unchanged from r9.
// ---------------------------------------------------------------------------
__global__ __launch_bounds__(256) void prep_T_pass(
    const float* __restrict__ img, float* __restrict__ T, int v0, int nv)
{
    __shared__ float tile[16 * 8 * 85];
    const int b = blockIdx.x, t = threadIdx.x;
    const int y = b >> 3, xs = (b & 7) << 4;
    const int total = 16 * 8 * nv;
    const float* src = img + (size_t)(y * 128 + xs) * 648;
    for (int i = t; i < total; i += 256) {
        const int x = i / (8 * nv);
        const int rem = i - x * (8 * nv);
        const int c = rem / nv;
        const int vi = rem - c * nv;
        tile[(x * 8 + c) * 85 + vi] = src[x * 648 + c * 81 + v0 + vi];
    }
    __syncthreads();
    for (int i = t; i < total; i += 256) {
        const int vi = i >> 7;
        const int x = (i >> 3) & 15;
        const int c = i & 7;
        T[((size_t)(vi * 128 + y) * 128 + xs + x) * 8 + c] = tile[(x * 8 + c) * 85 + vi];
    }
}

__global__ __launch_bounds__(256) void build_pass(
    const float* __restrict__ delt, const float* __restrict__ xg,
    const float* __restrict__ T, const unsigned short* __restrict__ WtP,
    const float* __restrict__ bias, float* __restrict__ out,
    int kc0, int nkc, int first)
{
    __shared__ __align__(16) unsigned short Ahi[4][64][8];
    __shared__ __align__(16) unsigned short Alo[4][64][8];

    const int t = threadIdx.x;
    const int lane = t & 63;
    const int wv = t >> 6;
    const int pos_g = blockIdx.x * 64 + lane;
    const int h = pos_g >> 9;
    const int w = (pos_g >> 2) & 127;

    const float dlt = delt[pos_g];
    const float ix0 = fmaf((float)w, 128.0f / 127.0f, -0.5f);
    const float iy0 = fmaf((float)h, 128.0f / 127.0f, -0.5f);
    const int xgbase = (h * 128 + w) * 81;

    f32x4_t acc[2][2];
#pragma unroll
    for (int i = 0; i < 2; ++i)
#pragma unroll
        for (int j = 0; j < 2; ++j) acc[i][j] = (f32x4_t)0.0f;

    const int mrow = (wv & 1) * 32;
    const int ncol = (wv >> 1) * 32;
    const int frow = lane & 15;
    const int fg = lane >> 4;

    for (int ci = 0; ci < nkc; ++ci) {
        const int kc = kc0 + ci;
        const int v = kc * 4 + wv;
        float sc0=0.f,sc1=0.f,sc2=0.f,sc3=0.f,sc4=0.f,sc5=0.f,sc6=0.f,sc7=0.f;
        float gate = 0.0f;
        if (v < 81) {
            gate = xg[xgbase + v];
            const int uu = v % 9, vv = v / 9;
            const float ix = fmaf((float)(4 - uu), dlt, ix0);
            const float iy = fmaf((float)(4 - vv), dlt, iy0);
            const float x0f = floorf(ix), y0f = floorf(iy);
            const float wx1 = ix - x0f, wy1 = iy - y0f;
            const float wx0 = 1.0f - wx1, wy0 = 1.0f - wy1;
            const int x0 = (int)x0f, y0 = (int)y0f;
            const int x1 = x0 + 1, y1 = y0 + 1;
            const float ex0 = (x0 >= 0 && x0 < 128) ? wx0 : 0.0f;
            const float ex1 = (x1 >= 0 && x1 < 128) ? wx1 : 0.0f;
            const float ey0 = (y0 >= 0 && y0 < 128) ? wy0 : 0.0f;
            const float ey1 = (y1 >= 0 && y1 < 128) ? wy1 : 0.0f;
            const int xc0 = min(max(x0, 0), 127), xc1 = min(max(x1, 0), 127);
            const int yc0 = min(max(y0, 0), 127), yc1 = min(max(y1, 0), 127);
            const float* bv = T + (size_t)(ci * 4 + wv) * VIEW_FLOATS;
            const float4* p00 = (const float4*)(bv + (yc0 * 128 + xc0) * 8);
            const float4* p01 = (const float4*)(bv + (yc0 * 128 + xc1) * 8);
            const float4* p10 = (const float4*)(bv + (yc1 * 128 + xc0) * 8);
            const float4* p11 = (const float4*)(bv + (yc1 * 128 + xc1) * 8);
            const float w00 = ex0 * ey0, w01 = ex1 * ey0;
            const float w10 = ex0 * ey1, w11 = ex1 * ey1;
            const float4 a00 = p00[0], b00 = p00[1];
            const float4 a01 = p01[0], b01 = p01[1];
            const float4 a10 = p10[0], b10 = p10[1];
            const float4 a11 = p11[0], b11 = p11[1];
            sc0 = fmaf(w11, a11.x, fmaf(w10, a10.x, fmaf(w01, a01.x, w00 * a00.x)));
            sc1 = fmaf(w11, a11.y, fmaf(w10, a10.y, fmaf(w01, a01.y, w00 * a00.y)));
            sc2 = fmaf(w11, a11.z, fmaf(w10, a10.z, fmaf(w01, a01.z, w00 * a00.z)));
            sc3 = fmaf(w11, a11.w, fmaf(w10, a10.w, fmaf(w01, a01.w, w00 * a00.w)));
            sc4 = fmaf(w11, b11.x, fmaf(w10, b10.x, fmaf(w01, b01.x, w00 * b00.x)));
            sc5 = fmaf(w11, b11.y, fmaf(w10, b10.y, fmaf(w01, b01.y, w00 * b00.y)));
            sc6 = fmaf(w11, b11.z, fmaf(w10, b10.z, fmaf(w01, b01.z, w00 * b00.z)));
            sc7 = fmaf(w11, b11.w, fmaf(w10, b10.w, fmaf(w01, b01.w, w00 * b00.w)));
        }
        const float g0 = sc0 * gate, g1 = sc1 * gate, g2 = sc2 * gate, g3 = sc3 * gate;
        const float g4 = sc4 * gate, g5 = sc5 * gate, g6 = sc6 * gate, g7 = sc7 * gate;
        unsigned int lw0, lw1, lw2, lw3;
        const unsigned int hw0 = pack_pair(g0, g1, lw0);
        const unsigned int hw1 = pack_pair(g2, g3, lw1);
        const unsigned int hw2 = pack_pair(g4, g5, lw2);
        const unsigned int hw3 = pack_pair(g6, g7, lw3);
        *(uint4*)(&Ahi[wv][lane][0]) = make_uint4(hw0, hw1, hw2, hw3);
        *(uint4*)(&Alo[wv][lane][0]) = make_uint4(lw0, lw1, lw2, lw3);

        __syncthreads();

        bhalf8_t fa_hi[2], fa_lo[2], fw_hi[2], fw_lo[2];
#pragma unroll
        for (int i = 0; i < 2; ++i) {
            const int r = mrow + i * 16 + frow;
            fa_hi[i] = *(const bhalf8_t*)(&Ahi[fg][r][0]);
            fa_lo[i] = *(const bhalf8_t*)(&Alo[fg][r][0]);
        }
        const unsigned short* wbase = WtP + kc * 4096 + fg * 512;
#pragma unroll
        for (int j = 0; j < 2; ++j) {
            const int o = ncol + j * 16 + frow;
            fw_hi[j] = *(const bhalf8_t*)(wbase + o * 8);
            fw_lo[j] = *(const bhalf8_t*)(wbase + 2048 + o * 8);
        }
#pragma unroll
        for (int i = 0; i < 2; ++i)
#pragma unroll
            for (int j = 0; j < 2; ++j) {
                acc[i][j] = __builtin_amdgcn_mfma_f32_16x16x32_bf16(fa_hi[i], fw_hi[j], acc[i][j], 0, 0, 0);
                acc[i][j] = __builtin_amdgcn_mfma_f32_16x16x32_bf16(fa_lo[i], fw_hi[j], acc[i][j], 0, 0, 0);
                acc[i][j] = __builtin_amdgcn_mfma_f32_16x16x32_bf16(fa_hi[i], fw_lo[j], acc[i][j], 0, 0, 0);
            }
        __syncthreads();
    }

#pragma unroll
    for (int j = 0; j < 2; ++j) {
        const int o = ncol + j * 16 + frow;
        const float bb = bias[o];
#pragma unroll
        for (int i = 0; i < 2; ++i) {
            const int posb = blockIdx.x * 64 + mrow + i * 16 + (lane >> 4) * 4;
            float* dst = out + (size_t)o * NPOS + posb;
            if (first) {
                *(float4*)dst = make_float4(acc[i][j][0] + bb, acc[i][j][1] + bb,
                                            acc[i][j][2] + bb, acc[i][j][3] + bb);
            } else {
                float4 cur = *(const float4*)dst;
                *(float4*)dst = make_float4(cur.x + acc[i][j][0], cur.y + acc[i][j][1],
                                            cur.z + acc[i][j][2], cur.w + acc[i][j][3]);
            }
        }
    }
}

__global__ __launch_bounds__(256) void build_direct(
    const float* __restrict__ delt, const float* __restrict__ xg,
    const float* __restrict__ img, const float* __restrict__ cw,
    const float* __restrict__ bias, float* __restrict__ out)
{
    __shared__ __align__(16) unsigned short Ahi[4][64][8];
    __shared__ __align__(16) unsigned short Alo[4][64][8];

    const int t = threadIdx.x;
    const int lane = t & 63;
    const int wv = t >> 6;
    const int pos_g = blockIdx.x * 64 + lane;
    const int h = pos_g >> 9;
    const int w = (pos_g >> 2) & 127;

    const float dlt = delt[pos_g];
    const float ix0 = fmaf((float)w, 128.0f / 127.0f, -0.5f);
    const float iy0 = fmaf((float)h, 128.0f / 127.0f, -0.5f);
    const int xgbase = (h * 128 + w) * 81;

    f32x4_t acc[2][2];
#pragma unroll
    for (int i = 0; i < 2; ++i)
#pragma unroll
        for (int j = 0; j < 2; ++j) acc[i][j] = (f32x4_t)0.0f;

    const int mrow = (wv & 1) * 32;
    const int ncol = (wv >> 1) * 32;
    const int frow = lane & 15;
    const int fg = lane >> 4;

    for (int kc = 0; kc < KCHUNKS; ++kc) {
        const int v = kc * 4 + wv;
        float sc[8];
#pragma unroll
        for (int c = 0; c < 8; ++c) sc[c] = 0.0f;
        float gate = 0.0f;
        if (v < 81) {
            gate = xg[xgbase + v];
            const int uu = v % 9, vv = v / 9;
            const float ix = fmaf((float)(4 - uu), dlt, ix0);
            const float iy = fmaf((float)(4 - vv), dlt, iy0);
            const float x0f = floorf(ix), y0f = floorf(iy);
            const float wx1 = ix - x0f, wy1 = iy - y0f;
            const float wx0 = 1.0f - wx1, wy0 = 1.0f - wy1;
            const int x0 = (int)x0f, y0 = (int)y0f;
            const int x1 = x0 + 1, y1 = y0 + 1;
            const float ex0 = (x0 >= 0 && x0 < 128) ? wx0 : 0.0f;
            const float ex1 = (x1 >= 0 && x1 < 128) ? wx1 : 0.0f;
            const float ey0 = (y0 >= 0 && y0 < 128) ? wy0 : 0.0f;
            const float ey1 = (y1 >= 0 && y1 < 128) ? wy1 : 0.0f;
            const int xc0 = min(max(x0, 0), 127), xc1 = min(max(x1, 0), 127);
            const int yc0 = min(max(y0, 0), 127), yc1 = min(max(y1, 0), 127);
            const float cwt[4] = {ex0 * ey0, ex1 * ey0, ex0 * ey1, ex1 * ey1};
            const int cyx[4] = {yc0 * 128 + xc0, yc0 * 128 + xc1,
                                yc1 * 128 + xc0, yc1 * 128 + xc1};
#pragma unroll
            for (int k = 0; k < 4; ++k) {
                const float* p = img + (size_t)cyx[k] * 648 + v;
#pragma unroll
                for (int c = 0; c < 8; ++c)
                    sc[c] = fmaf(cwt[k], p[c * 81], sc[c]);
            }
        }
        unsigned int hw[4], lw[4];
#pragma unroll
        for (int q = 0; q < 4; ++q)
            hw[q] = pack_pair(sc[2 * q] * gate, sc[2 * q + 1] * gate, lw[q]);
        *(uint4*)(&Ahi[wv][lane][0]) = make_uint4(hw[0], hw[1], hw[2], hw[3]);
        *(uint4*)(&Alo[wv][lane][0]) = make_uint4(lw[0], lw[1], lw[2], lw[3]);

        __syncthreads();

        const int vW = kc * 4 + fg;
        bhalf8_t fw_hi[2], fw_lo[2];
#pragma unroll
        for (int j = 0; j < 2; ++j) {
            const int o = ncol + j * 16 + frow;
#pragma unroll
            for (int e = 0; e < 8; ++e) {
                const float val = (vW < 81) ? cw[o * 648 + e * 81 + vW] : 0.0f;
                const unsigned int hb = __float_as_uint(val) & 0xffff0000u;
                const float r = val - __uint_as_float(hb);
                fw_hi[j][e] = (short)(hb >> 16);
                fw_lo[j][e] = (short)(__float_as_uint(r) >> 16);
            }
        }
        bhalf8_t fa_hi[2], fa_lo[2];
#pragma unroll
        for (int i = 0; i < 2; ++i) {
            const int r = mrow + i * 16 + frow;
            fa_hi[i] = *(const bhalf8_t*)(&Ahi[fg][r][0]);
            fa_lo[i] = *(const bhalf8_t*)(&Alo[fg][r][0]);
        }
#pragma unroll
        for (int i = 0; i < 2; ++i)
#pragma unroll
            for (int j = 0; j < 2; ++j) {
                acc[i][j] = __builtin_amdgcn_mfma_f32_16x16x32_bf16(fa_hi[i], fw_hi[j], acc[i][j], 0, 0, 0);
                acc[i][j] = __builtin_amdgcn_mfma_f32_16x16x32_bf16(fa_lo[i], fw_hi[j], acc[i][j], 0, 0, 0);
                acc[i][j] = __builtin_amdgcn_mfma_f32_16x16x32_bf16(fa_hi[i], fw_lo[j], acc[i][j], 0, 0, 0);
            }
        __syncthreads();
    }

#pragma unroll
    for (int j = 0; j < 2; ++j) {
        const int o = ncol + j * 16 + frow;
        const float bb = bias[o];
#pragma unroll
        for (int i = 0; i < 2; ++i) {
            const int posb = blockIdx.x * 64 + mrow + i * 16 + (lane >> 4) * 4;
            float* dst = out + (size_t)o * NPOS + posb;
            *(float4*)dst = make_float4(acc[i][j][0] + bb, acc[i][j][1] + bb,
                                        acc[i][j][2] + bb, acc[i][j][3] + bb);
        }
    }
}

extern "C" void kernel_launch(void* const* d_in, const int* in_sizes, int n_in,
                              void* d_out, int out_size, void* d_ws, size_t ws_size,
                              hipStream_t stream)
{
    const float* deltmap = (const float*)d_in[0];
    const float* image   = (const float*)d_in[1];
    const float* xgp     = (const float*)d_in[2];
    const float* cw      = (const float*)d_in[3];
    const float* cb      = (const float*)d_in[4];
    float* outp = (float*)d_out;

    unsigned short* WtP = (unsigned short*)d_ws;
    float* T    = (float*)((char*)d_ws + W_BYTES);
    float* part = (float*)((char*)d_ws + W_BYTES + T_BYTES);

    const bool okT    = ws_size >= (size_t)W_BYTES + T_BYTES;
    const bool okPart = ws_size >= (size_t)W_BYTES + T_BYTES + PART_BYTES;

    if (okT) {
        prep_w_kernel<<<64, 256, 0, stream>>>(cw, WtP);
        prep_T_all<<<1024, 256, 0, stream>>>(image, T);
        if (okPart) {
            build_ksplit<<<dim3(NBLK, 2), 256, 0, stream>>>(deltmap, xgp, T, WtP,
                                                            cb, outp, part, 2);
            reduce_kernel<<<4096, 256, 0, stream>>>(part, outp);
        } else {
            build_ksplit<<<dim3(NBLK, 1), 256, 0, stream>>>(deltmap, xgp, T, WtP,
                                                            cb, outp, part, 1);
        }
    } else {
        long long availT = (long long)ws_size - (long long)W_BYTES;
        int G = 0;
        if (availT > 0) {
            long long g = availT / CHUNK_BYTES;
            G = (g > 21) ? 21 : (int)g;
        }
        if (G >= 1) {
            prep_w_kernel<<<64, 256, 0, stream>>>(cw, WtP);
            int first = 1;
            for (int kc0 = 0; kc0 < KCHUNKS; kc0 += G) {
                const int nkc = (KCHUNKS - kc0 < G) ? (KCHUNKS - kc0) : G;
                const int v0 = kc0 * 4;
                int nv = 81 - v0;
                if (nv > nkc * 4) nv = nkc * 4;
                prep_T_pass<<<1024, 256, 0, stream>>>(image, T, v0, nv);
                build_pass<<<NBLK, 256, 0, stream>>>(deltmap, xgp, T, WtP, cb, outp,
                                                     kc0, nkc, first);
                first = 0;
            }
        } else {
            build_direct<<<NBLK, 256, 0, stream>>>(deltmap, xgp, image, cw, cb, outp);
        }
    }
}